// Round 1
// baseline (307.591 us; speedup 1.0000x reference)
//
#include <hip/hip_runtime.h>
#include <hip/hip_bf16.h>

#define M_ROWS 256
#define T_LEN  1024
#define NLAG   2048
#define GSTRIDE 2064   // 258*8 elements; row byte stride 4128 (16B multiple)

typedef __attribute__((ext_vector_type(8))) __bf16 bf16x8;
typedef __attribute__((ext_vector_type(4))) float  f32x4;
typedef __attribute__((ext_vector_type(4))) unsigned int u32x4;

static __device__ __forceinline__ unsigned short f2bf(float f) {
  unsigned int u = __builtin_bit_cast(unsigned int, f);
  u += 0x7FFFu + ((u >> 16) & 1u);   // RNE
  return (unsigned short)(u >> 16);
}

// ---------------- prep: center rows, bf16-ify, std(ddof=1) ----------------
__global__ __launch_bounds__(256) void prep_kernel(
    const float* __restrict__ zis, const float* __restrict__ zjs,
    unsigned short* __restrict__ f1c, unsigned short* __restrict__ f2c,
    float* __restrict__ s1, float* __restrict__ s2) {
  int r = blockIdx.x;  // 0..511
  const float* src = (r < M_ROWS) ? (zis + r * T_LEN) : (zjs + (r - M_ROWS) * T_LEN);
  unsigned short* dst = (r < M_ROWS) ? (f1c + r * T_LEN) : (f2c + (r - M_ROWS) * T_LEN);
  float* sdst = (r < M_ROWS) ? (s1 + r) : (s2 + (r - M_ROWS));
  int t = threadIdx.x;
  float4 v = reinterpret_cast<const float4*>(src)[t];
  float ls = v.x + v.y + v.z + v.w;
  for (int m = 1; m <= 32; m <<= 1) ls += __shfl_xor(ls, m, 64);
  __shared__ float red[4];
  __shared__ float red2[4];
  if ((t & 63) == 0) red[t >> 6] = ls;
  __syncthreads();
  float mean = (red[0] + red[1] + red[2] + red[3]) * (1.0f / 1024.0f);
  float c0 = v.x - mean, c1 = v.y - mean, c2 = v.z - mean, c3 = v.w - mean;
  float ss = c0 * c0 + c1 * c1 + c2 * c2 + c3 * c3;
  for (int m = 1; m <= 32; m <<= 1) ss += __shfl_xor(ss, m, 64);
  if ((t & 63) == 0) red2[t >> 6] = ss;
  __syncthreads();
  float sd = sqrtf((red2[0] + red2[1] + red2[2] + red2[3]) * (1.0f / 1023.0f));
  if (t == 0) *sdst = sd;
  ushort4 o;
  o.x = f2bf(c0); o.y = f2bf(c1); o.z = f2bf(c2); o.w = f2bf(c3);
  reinterpret_cast<ushort4*>(dst)[t] = o;
}

// ---------------- Toeplitz-GEMM correlation + per-row lag-max ----------------
// grid: wg = ((chunk*2 + iblk)*256 + j), 2048 wgs, 256 threads (4 waves, 2x2)
__global__ __launch_bounds__(256) void corr_kernel(
    const unsigned short* __restrict__ f1c,
    const unsigned short* __restrict__ f2c,
    float* __restrict__ part) {
  __shared__ __align__(16) unsigned short gall[8 * GSTRIDE];  // 33 KB
  __shared__ float red[128];

  int wg = blockIdx.x;
  int j = wg & 255;
  int iblk = (wg >> 8) & 1;
  int chunk = wg >> 9;  // 0..3

  int tid = threadIdx.x;
  int lane = tid & 63;
  int w = tid >> 6;
  int wx = w & 1;   // lag half
  int wy = w >> 1;  // row half
  int lo = lane & 15;
  int hi = lane >> 4;

  // ---- fill 8 shifted copies g_r[x] = gp[(x-r) mod 2048], gp = f2 row zero-padded ----
  {
    const unsigned short* f2row = f2c + j * T_LEN;
    for (int task = tid; task < 8 * 258; task += 256) {
      int r = task / 258;
      int x0 = (task - r * 258) * 8;
      unsigned int pk0, pk1, pk2, pk3;
      unsigned short v0, v1, v2, v3, v4, v5, v6, v7;
      int m;
      m = (x0 + 0 - r) & (NLAG - 1); v0 = (m < T_LEN) ? f2row[m] : 0;
      m = (x0 + 1 - r) & (NLAG - 1); v1 = (m < T_LEN) ? f2row[m] : 0;
      m = (x0 + 2 - r) & (NLAG - 1); v2 = (m < T_LEN) ? f2row[m] : 0;
      m = (x0 + 3 - r) & (NLAG - 1); v3 = (m < T_LEN) ? f2row[m] : 0;
      m = (x0 + 4 - r) & (NLAG - 1); v4 = (m < T_LEN) ? f2row[m] : 0;
      m = (x0 + 5 - r) & (NLAG - 1); v5 = (m < T_LEN) ? f2row[m] : 0;
      m = (x0 + 6 - r) & (NLAG - 1); v6 = (m < T_LEN) ? f2row[m] : 0;
      m = (x0 + 7 - r) & (NLAG - 1); v7 = (m < T_LEN) ? f2row[m] : 0;
      pk0 = (unsigned int)v0 | ((unsigned int)v1 << 16);
      pk1 = (unsigned int)v2 | ((unsigned int)v3 << 16);
      pk2 = (unsigned int)v4 | ((unsigned int)v5 << 16);
      pk3 = (unsigned int)v6 | ((unsigned int)v7 << 16);
      u32x4 pk; pk[0] = pk0; pk[1] = pk1; pk[2] = pk2; pk[3] = pk3;
      *reinterpret_cast<u32x4*>(&gall[r * GSTRIDE + x0]) = pk;
    }
  }
  __syncthreads();

  // A fragment base pointers (per 16-row subtile)
  const unsigned short* aptr[4];
#pragma unroll
  for (int af = 0; af < 4; ++af) {
    int row = iblk * 128 + wy * 64 + af * 16 + lo;
    aptr[af] = f1c + row * T_LEN + hi * 8;
  }

  float rowmax = -3.4e38f;  // used by tid<128

  for (int tb = 0; tb < 4; ++tb) {
    int tau0 = tb * 512 + chunk * 128;  // strided for load balance

    // nonzero k-step range: tile zero iff m_lo in [1024, 1889]
    int kA = 32, kB = 0;
    for (int c = 0; c < 32; ++c) {
      int mlo = (c * 32 - tau0 - 127) & (NLAG - 1);
      if (!(mlo >= 1024 && mlo <= 1889)) { if (c < kA) kA = c; kB = c + 1; }
    }

    f32x4 acc[4][4];
#pragma unroll
    for (int a0 = 0; a0 < 4; ++a0)
#pragma unroll
      for (int b0 = 0; b0 < 4; ++b0) acc[a0][b0] = f32x4{0.f, 0.f, 0.f, 0.f};

    for (int ks = kA; ks < kB; ++ks) {
      int k0 = ks * 32;
      bf16x8 av[4], bv[4];
#pragma unroll
      for (int a0 = 0; a0 < 4; ++a0)
        av[a0] = *reinterpret_cast<const bf16x8*>(aptr[a0] + k0);
#pragma unroll
      for (int b0 = 0; b0 < 4; ++b0) {
        int rp = wx * 4 + b0;  // shift-phase r' of this fragment
        int x0 = ((k0 + hi * 8 - tau0 - rp - lo * 8) & (NLAG - 1)) + rp;  // 8-aligned
        bv[b0] = *reinterpret_cast<const bf16x8*>(&gall[rp * GSTRIDE + x0]);
      }
#pragma unroll
      for (int a0 = 0; a0 < 4; ++a0)
#pragma unroll
        for (int b0 = 0; b0 < 4; ++b0)
          acc[a0][b0] = __builtin_amdgcn_mfma_f32_16x16x32_bf16(av[a0], bv[b0], acc[a0][b0], 0, 0, 0);
    }

    // per-row max over this tau-block's 128 lags
    float vmax[4][4];
#pragma unroll
    for (int a0 = 0; a0 < 4; ++a0)
#pragma unroll
      for (int q = 0; q < 4; ++q) {
        float v = fmaxf(fmaxf(acc[a0][0][q], acc[a0][1][q]),
                        fmaxf(acc[a0][2][q], acc[a0][3][q]));
        v = fmaxf(v, __shfl_xor(v, 1, 64));
        v = fmaxf(v, __shfl_xor(v, 2, 64));
        v = fmaxf(v, __shfl_xor(v, 4, 64));
        v = fmaxf(v, __shfl_xor(v, 8, 64));
        vmax[a0][q] = v;
      }
    if (wx == 0 && lo == 0) {
#pragma unroll
      for (int a0 = 0; a0 < 4; ++a0)
#pragma unroll
        for (int q = 0; q < 4; ++q)
          red[wy * 64 + a0 * 16 + hi * 4 + q] = vmax[a0][q];
    }
    __syncthreads();
    if (wx == 1 && lo == 0) {
#pragma unroll
      for (int a0 = 0; a0 < 4; ++a0)
#pragma unroll
        for (int q = 0; q < 4; ++q) {
          int idx = wy * 64 + a0 * 16 + hi * 4 + q;
          red[idx] = fmaxf(red[idx], vmax[a0][q]);
        }
    }
    __syncthreads();
    if (tid < 128) rowmax = fmaxf(rowmax, red[tid]);
    __syncthreads();
  }

  if (tid < 128) {
    int i = iblk * 128 + tid;
    part[(j * 4 + chunk) * 256 + i] = rowmax;
  }
}

// ---------------- per-row CE: dist, logsumexp, pick target ----------------
__global__ __launch_bounds__(256) void loss_kernel(
    const float* __restrict__ part, const float* __restrict__ s1,
    const float* __restrict__ s2, const int* __restrict__ speeds,
    float* __restrict__ lossrows) {
  int i = blockIdx.x;
  int jt = threadIdx.x;
  float m = part[(jt * 4 + 0) * 256 + i];
  m = fmaxf(m, part[(jt * 4 + 1) * 256 + i]);
  m = fmaxf(m, part[(jt * 4 + 2) * 256 + i]);
  m = fmaxf(m, part[(jt * 4 + 3) * 256 + i]);
  float p = s1[i] * s2[jt];
  p = (p == 0.0f) ? 1.0f : p;
  float d = m / (p * 1023.0f);

  float t = d;
  for (int mk = 1; mk <= 32; mk <<= 1) t = fmaxf(t, __shfl_xor(t, mk, 64));
  __shared__ float wmax[4], wsum[4], sel;
  if ((jt & 63) == 0) wmax[jt >> 6] = t;
  if (jt == speeds[i]) sel = d;
  __syncthreads();
  float rmax = fmaxf(fmaxf(wmax[0], wmax[1]), fmaxf(wmax[2], wmax[3]));
  float e = expf(d - rmax);
  for (int mk = 1; mk <= 32; mk <<= 1) e += __shfl_xor(e, mk, 64);
  if ((jt & 63) == 0) wsum[jt >> 6] = e;
  __syncthreads();
  if (jt == 0) {
    float sum = wsum[0] + wsum[1] + wsum[2] + wsum[3];
    lossrows[i] = rmax + logf(sum) - sel;
  }
}

__global__ __launch_bounds__(256) void sum_kernel(const float* __restrict__ lossrows,
                                                  float* __restrict__ out) {
  int t = threadIdx.x;
  float v = lossrows[t];
  for (int mk = 1; mk <= 32; mk <<= 1) v += __shfl_xor(v, mk, 64);
  __shared__ float wsh[4];
  if ((t & 63) == 0) wsh[t >> 6] = v;
  __syncthreads();
  if (t == 0) out[0] = wsh[0] + wsh[1] + wsh[2] + wsh[3];
}

extern "C" void kernel_launch(void* const* d_in, const int* in_sizes, int n_in,
                              void* d_out, int out_size, void* d_ws, size_t ws_size,
                              hipStream_t stream) {
  (void)in_sizes; (void)n_in; (void)out_size; (void)ws_size;
  const float* zis = (const float*)d_in[0];
  const float* zjs = (const float*)d_in[1];
  const int* speeds = (const int*)d_in[2];
  float* out = (float*)d_out;

  char* ws = (char*)d_ws;
  unsigned short* f1c = (unsigned short*)ws;                       // 512 KB
  unsigned short* f2c = (unsigned short*)(ws + 524288);            // 512 KB
  float* s1 = (float*)(ws + 1048576);                              // 1 KB
  float* s2 = (float*)(ws + 1048576 + 1024);                       // 1 KB
  float* part = (float*)(ws + 1048576 + 2048);                     // 1 MB: [j][chunk][i]
  float* lossrows = (float*)(ws + 1048576 + 2048 + 1048576);       // 1 KB

  prep_kernel<<<512, 256, 0, stream>>>(zis, zjs, f1c, f2c, s1, s2);
  corr_kernel<<<2048, 256, 0, stream>>>(f1c, f2c, part);
  loss_kernel<<<256, 256, 0, stream>>>(part, s1, s2, speeds, lossrows);
  sum_kernel<<<1, 256, 0, stream>>>(lossrows, out);
}

// Round 2
// 185.233 us; speedup vs baseline: 1.6606x; 1.6606x over previous
//
#include <hip/hip_runtime.h>
#include <hip/hip_bf16.h>

#define M_ROWS 256
#define T_LEN  1024
#define NLAG   2048
#define GSTRIDE 2072   // 2048 + 24 tail; 4144B row stride => copies hit disjoint banks

typedef __attribute__((ext_vector_type(8)))  __bf16 bf16x8;
typedef __attribute__((ext_vector_type(16))) float  f32x16;
typedef __attribute__((ext_vector_type(4)))  unsigned int u32x4;

static __device__ __forceinline__ unsigned short f2bf(float f) {
  unsigned int u = __builtin_bit_cast(unsigned int, f);
  u += 0x7FFFu + ((u >> 16) & 1u);   // RNE
  return (unsigned short)(u >> 16);
}

// ---------------- prep: center rows, bf16-ify, std(ddof=1) ----------------
// f1 -> packed fragment layout f1p[kg][row][8]  (kg = k/8), f2 -> row-major
__global__ __launch_bounds__(256) void prep_kernel(
    const float* __restrict__ zis, const float* __restrict__ zjs,
    unsigned short* __restrict__ f1p, unsigned short* __restrict__ f2c,
    float* __restrict__ s1, float* __restrict__ s2) {
  int r = blockIdx.x;  // 0..511
  const float* src = (r < M_ROWS) ? (zis + r * T_LEN) : (zjs + (r - M_ROWS) * T_LEN);
  int t = threadIdx.x;
  float4 v = reinterpret_cast<const float4*>(src)[t];
  float ls = v.x + v.y + v.z + v.w;
  for (int m = 1; m <= 32; m <<= 1) ls += __shfl_xor(ls, m, 64);
  __shared__ float red[4];
  __shared__ float red2[4];
  if ((t & 63) == 0) red[t >> 6] = ls;
  __syncthreads();
  float mean = (red[0] + red[1] + red[2] + red[3]) * (1.0f / 1024.0f);
  float c0 = v.x - mean, c1 = v.y - mean, c2 = v.z - mean, c3 = v.w - mean;
  float ss = c0 * c0 + c1 * c1 + c2 * c2 + c3 * c3;
  for (int m = 1; m <= 32; m <<= 1) ss += __shfl_xor(ss, m, 64);
  if ((t & 63) == 0) red2[t >> 6] = ss;
  __syncthreads();
  float sd = sqrtf((red2[0] + red2[1] + red2[2] + red2[3]) * (1.0f / 1023.0f));
  ushort4 o;
  o.x = f2bf(c0); o.y = f2bf(c1); o.z = f2bf(c2); o.w = f2bf(c3);
  if (r < M_ROWS) {
    if (t == 0) s1[r] = sd;
    // positions 4t..4t+3 -> kg = t>>1, element offset (t&1)*4
    reinterpret_cast<ushort4*>(&f1p[(((t >> 1) * 256) + r) * 8 + (t & 1) * 4])[0] = o;
  } else {
    if (t == 0) s2[r - M_ROWS] = sd;
    reinterpret_cast<ushort4*>(&f2c[(r - M_ROWS) * T_LEN + 4 * t])[0] = o;
  }
}

// ---------------- Toeplitz-GEMM correlation + per-row lag-max ----------------
// grid: wg = (chunk*2 + iblk)*256 + j ; 2048 wgs, 256 threads (4 waves, wy x wx)
__global__ __launch_bounds__(256, 4) void corr_kernel(
    const unsigned short* __restrict__ f1p,
    const unsigned short* __restrict__ f2c,
    float* __restrict__ part) {
  __shared__ __align__(16) unsigned short gall[8 * GSTRIDE];  // 33152 B
  __shared__ __align__(16) unsigned short gpz[2048];          // 4096 B: row + zero pad
  __shared__ float red[2][128];                               // 1024 B

  int wg = blockIdx.x;
  int j = wg & 255;
  int iblk = (wg >> 8) & 1;
  int chunk = wg >> 9;  // 0..3

  int tid = threadIdx.x;
  int lane = tid & 63;
  int w = tid >> 6;
  int wx = w & 1;   // lag half
  int wy = w >> 1;  // row half
  int l5 = lane >> 5;
  int lq = (lane >> 3) & 3;
  int lr = lane & 7;
  int l31 = lane & 31;

  // stage gpz = centered f2 row, zero-padded to 2048
  if (tid < 128) {
    u32x4 v = *reinterpret_cast<const u32x4*>(f2c + j * T_LEN + tid * 8);
    *reinterpret_cast<u32x4*>(&gpz[tid * 8]) = v;
  } else {
    u32x4 z; z[0] = z[1] = z[2] = z[3] = 0;
    *reinterpret_cast<u32x4*>(&gpz[1024 + (tid - 128) * 8]) = z;
  }
  __syncthreads();

  // build 8 shifted copies g_r[x] = gpz[(x - r) & 2047], x in [0, 2072)
  for (int r = 0; r < 8; ++r) {
    for (int c = tid; c < 259; c += 256) {
      int x0 = c * 8;
      unsigned int u[4];
#pragma unroll
      for (int h = 0; h < 4; ++h) {
        int i0 = (x0 + 2 * h - r) & (NLAG - 1);
        int i1 = (x0 + 2 * h + 1 - r) & (NLAG - 1);
        u[h] = (unsigned int)gpz[i0] | ((unsigned int)gpz[i1] << 16);
      }
      u32x4 pk; pk[0] = u[0]; pk[1] = u[1]; pk[2] = u[2]; pk[3] = u[3];
      *reinterpret_cast<u32x4*>(&gall[r * GSTRIDE + x0]) = pk;
    }
  }
  __syncthreads();

  int rowb = iblk * 128 + wy * 64;
  // A base: element ((ks*4 + ksub*2 + l5)*256 + row)*8 ; rf -> +256 elem, ksub -> +4096 elem
  const unsigned short* abase = f1p + ((l5 * 256) + rowb + l31) * 8;
  int bb = lr * GSTRIDE;

  float rowmax = -3.4e38f;  // rows owned by tid<128

  for (int tb = 0; tb < 4; ++tb) {
    int tau0 = tb * 512 + chunk * 128;  // strided for load balance
    int kA, kB;
    if (tau0 < 1024) { kA = tau0 >> 5; kB = 32; }
    else             { kA = 0;         kB = ((tau0 - 898) >> 5) + 1; }

    int yc0 = 8 * l5 - 8 * lq - tau0 - wx * 64;  // lag frag c=0
    int yc1 = yc0 - 32;                          // lag frag c=1

    f32x16 acc00, acc01, acc10, acc11;
#pragma unroll
    for (int q = 0; q < 16; ++q) { acc00[q] = 0.f; acc01[q] = 0.f; acc10[q] = 0.f; acc11[q] = 0.f; }

    const unsigned short* ap0 = abase + kA * 8192;
    const unsigned short* ap1 = ap0 + 4096;

    for (int ks = kA; ks < kB; ++ks) {
      int kbase = ks * 32;
      int y0 = (yc0 + kbase) & (NLAG - 1);
      int y1 = (yc1 + kbase) & (NLAG - 1);
      bf16x8 a00 = *reinterpret_cast<const bf16x8*>(ap0);        // rf0 ksub0
      bf16x8 a10 = *reinterpret_cast<const bf16x8*>(ap0 + 256);  // rf1 ksub0
      bf16x8 a01 = *reinterpret_cast<const bf16x8*>(ap1);        // rf0 ksub1
      bf16x8 a11 = *reinterpret_cast<const bf16x8*>(ap1 + 256);  // rf1 ksub1
      bf16x8 b00 = *reinterpret_cast<const bf16x8*>(&gall[bb + y0]);       // c0 ksub0
      bf16x8 b01 = *reinterpret_cast<const bf16x8*>(&gall[bb + y0 + 16]);  // c0 ksub1
      bf16x8 b10 = *reinterpret_cast<const bf16x8*>(&gall[bb + y1]);       // c1 ksub0
      bf16x8 b11 = *reinterpret_cast<const bf16x8*>(&gall[bb + y1 + 16]);  // c1 ksub1
      acc00 = __builtin_amdgcn_mfma_f32_32x32x16_bf16(a00, b00, acc00, 0, 0, 0);
      acc01 = __builtin_amdgcn_mfma_f32_32x32x16_bf16(a00, b10, acc01, 0, 0, 0);
      acc10 = __builtin_amdgcn_mfma_f32_32x32x16_bf16(a10, b00, acc10, 0, 0, 0);
      acc11 = __builtin_amdgcn_mfma_f32_32x32x16_bf16(a10, b10, acc11, 0, 0, 0);
      acc00 = __builtin_amdgcn_mfma_f32_32x32x16_bf16(a01, b01, acc00, 0, 0, 0);
      acc01 = __builtin_amdgcn_mfma_f32_32x32x16_bf16(a01, b11, acc01, 0, 0, 0);
      acc10 = __builtin_amdgcn_mfma_f32_32x32x16_bf16(a11, b01, acc10, 0, 0, 0);
      acc11 = __builtin_amdgcn_mfma_f32_32x32x16_bf16(a11, b11, acc11, 0, 0, 0);
      ap0 += 8192; ap1 += 8192;
    }

    // per-row max: combine lag frags, reduce across 32 lanes (cols)
    float* redw = &red[wx][wy * 64];
#pragma unroll
    for (int rf = 0; rf < 2; ++rf) {
#pragma unroll
      for (int q = 0; q < 16; ++q) {
        float v = rf ? fmaxf(acc10[q], acc11[q]) : fmaxf(acc00[q], acc01[q]);
        v = fmaxf(v, __shfl_xor(v, 1, 64));
        v = fmaxf(v, __shfl_xor(v, 2, 64));
        v = fmaxf(v, __shfl_xor(v, 4, 64));
        v = fmaxf(v, __shfl_xor(v, 8, 64));
        v = fmaxf(v, __shfl_xor(v, 16, 64));
        if (l31 == 0) redw[rf * 32 + (q & 3) + 8 * (q >> 2) + 4 * l5] = v;
      }
    }
    __syncthreads();
    if (tid < 128) rowmax = fmaxf(rowmax, fmaxf(red[0][tid], red[1][tid]));
    __syncthreads();
  }

  if (tid < 128) part[(j * 4 + chunk) * 256 + iblk * 128 + tid] = rowmax;
}

// ---------------- per-row CE: dist, logsumexp, pick target ----------------
__global__ __launch_bounds__(256) void loss_kernel(
    const float* __restrict__ part, const float* __restrict__ s1,
    const float* __restrict__ s2, const int* __restrict__ speeds,
    float* __restrict__ lossrows) {
  int i = blockIdx.x;
  int jt = threadIdx.x;
  float m = part[(jt * 4 + 0) * 256 + i];
  m = fmaxf(m, part[(jt * 4 + 1) * 256 + i]);
  m = fmaxf(m, part[(jt * 4 + 2) * 256 + i]);
  m = fmaxf(m, part[(jt * 4 + 3) * 256 + i]);
  float p = s1[i] * s2[jt];
  p = (p == 0.0f) ? 1.0f : p;
  float d = m / (p * 1023.0f);

  float t = d;
  for (int mk = 1; mk <= 32; mk <<= 1) t = fmaxf(t, __shfl_xor(t, mk, 64));
  __shared__ float wmax[4], wsum[4], sel;
  if ((jt & 63) == 0) wmax[jt >> 6] = t;
  if (jt == speeds[i]) sel = d;
  __syncthreads();
  float rmax = fmaxf(fmaxf(wmax[0], wmax[1]), fmaxf(wmax[2], wmax[3]));
  float e = expf(d - rmax);
  for (int mk = 1; mk <= 32; mk <<= 1) e += __shfl_xor(e, mk, 64);
  if ((jt & 63) == 0) wsum[jt >> 6] = e;
  __syncthreads();
  if (jt == 0) {
    float sum = wsum[0] + wsum[1] + wsum[2] + wsum[3];
    lossrows[i] = rmax + logf(sum) - sel;
  }
}

__global__ __launch_bounds__(256) void sum_kernel(const float* __restrict__ lossrows,
                                                  float* __restrict__ out) {
  int t = threadIdx.x;
  float v = lossrows[t];
  for (int mk = 1; mk <= 32; mk <<= 1) v += __shfl_xor(v, mk, 64);
  __shared__ float wsh[4];
  if ((t & 63) == 0) wsh[t >> 6] = v;
  __syncthreads();
  if (t == 0) out[0] = wsh[0] + wsh[1] + wsh[2] + wsh[3];
}

extern "C" void kernel_launch(void* const* d_in, const int* in_sizes, int n_in,
                              void* d_out, int out_size, void* d_ws, size_t ws_size,
                              hipStream_t stream) {
  (void)in_sizes; (void)n_in; (void)out_size; (void)ws_size;
  const float* zis = (const float*)d_in[0];
  const float* zjs = (const float*)d_in[1];
  const int* speeds = (const int*)d_in[2];
  float* out = (float*)d_out;

  char* ws = (char*)d_ws;
  unsigned short* f1p = (unsigned short*)ws;                       // 512 KB packed A
  unsigned short* f2c = (unsigned short*)(ws + 524288);            // 512 KB
  float* s1 = (float*)(ws + 1048576);                              // 1 KB
  float* s2 = (float*)(ws + 1048576 + 1024);                       // 1 KB
  float* part = (float*)(ws + 1048576 + 2048);                     // 1 MB: [j][chunk][i]
  float* lossrows = (float*)(ws + 1048576 + 2048 + 1048576);       // 1 KB

  prep_kernel<<<512, 256, 0, stream>>>(zis, zjs, f1p, f2c, s1, s2);
  corr_kernel<<<2048, 256, 0, stream>>>(f1p, f2c, part);
  loss_kernel<<<256, 256, 0, stream>>>(part, s1, s2, speeds, lossrows);
  sum_kernel<<<1, 256, 0, stream>>>(lossrows, out);
}

// Round 3
// 173.030 us; speedup vs baseline: 1.7777x; 1.0705x over previous
//
#include <hip/hip_runtime.h>
#include <hip/hip_bf16.h>

#define M_ROWS 256
#define T_LEN  1024
#define NLAG   2048
#define GSTRIDE 2072   // 2048 + 24 tail; word stride 1036 ≡ 12 mod 32 -> copies on disjoint banks

typedef __attribute__((ext_vector_type(8)))  __bf16 bf16x8;
typedef __attribute__((ext_vector_type(16))) float  f32x16;
typedef __attribute__((ext_vector_type(4)))  unsigned int u32x4;

static __device__ __forceinline__ unsigned short f2bf(float f) {
  unsigned int u = __builtin_bit_cast(unsigned int, f);
  u += 0x7FFFu + ((u >> 16) & 1u);   // RNE
  return (unsigned short)(u >> 16);
}

// ---------------- prep: center rows, bf16-ify, std(ddof=1) ----------------
// f1 -> packed fragment layout f1p[kg][row][8]  (kg = k/8), f2 -> row-major
__global__ __launch_bounds__(256) void prep_kernel(
    const float* __restrict__ zis, const float* __restrict__ zjs,
    unsigned short* __restrict__ f1p, unsigned short* __restrict__ f2c,
    float* __restrict__ s1, float* __restrict__ s2) {
  int r = blockIdx.x;  // 0..511
  const float* src = (r < M_ROWS) ? (zis + r * T_LEN) : (zjs + (r - M_ROWS) * T_LEN);
  int t = threadIdx.x;
  float4 v = reinterpret_cast<const float4*>(src)[t];
  float ls = v.x + v.y + v.z + v.w;
  for (int m = 1; m <= 32; m <<= 1) ls += __shfl_xor(ls, m, 64);
  __shared__ float red[4];
  __shared__ float red2[4];
  if ((t & 63) == 0) red[t >> 6] = ls;
  __syncthreads();
  float mean = (red[0] + red[1] + red[2] + red[3]) * (1.0f / 1024.0f);
  float c0 = v.x - mean, c1 = v.y - mean, c2 = v.z - mean, c3 = v.w - mean;
  float ss = c0 * c0 + c1 * c1 + c2 * c2 + c3 * c3;
  for (int m = 1; m <= 32; m <<= 1) ss += __shfl_xor(ss, m, 64);
  if ((t & 63) == 0) red2[t >> 6] = ss;
  __syncthreads();
  float sd = sqrtf((red2[0] + red2[1] + red2[2] + red2[3]) * (1.0f / 1023.0f));
  ushort4 o;
  o.x = f2bf(c0); o.y = f2bf(c1); o.z = f2bf(c2); o.w = f2bf(c3);
  if (r < M_ROWS) {
    if (t == 0) s1[r] = sd;
    reinterpret_cast<ushort4*>(&f1p[(((t >> 1) * 256) + r) * 8 + (t & 1) * 4])[0] = o;
  } else {
    if (t == 0) s2[r - M_ROWS] = sd;
    reinterpret_cast<ushort4*>(&f2c[(r - M_ROWS) * T_LEN + 4 * t])[0] = o;
  }
}

// ---------------- Toeplitz-GEMM correlation + per-row lag-max ----------------
// grid: wg = (chunk*2 + iblk)*256 + j ; 2048 wgs, 256 threads (4 waves, wy x wx)
__global__ __launch_bounds__(256, 4) void corr_kernel(
    const unsigned short* __restrict__ f1p,
    const unsigned short* __restrict__ f2c,
    float* __restrict__ part) {
  __shared__ __align__(16) unsigned short gall[8 * GSTRIDE];  // 33152 B
  __shared__ float red[2][128];                               // 1024 B

  int wg = blockIdx.x;
  int j = wg & 255;
  int iblk = (wg >> 8) & 1;
  int chunk = wg >> 9;  // 0..3

  int tid = threadIdx.x;
  int lane = tid & 63;
  int w = tid >> 6;
  int wx = w & 1;   // lag half
  int wy = w >> 1;  // row half
  int l5 = lane >> 5;
  int lq = (lane >> 3) & 3;
  int lr = lane & 7;
  int l31 = lane & 31;

  // ---- step A: copy 0 = centered f2 row, zero-padded, +24-elem wrap tail ----
  {
    const unsigned short* f2row = f2c + j * T_LEN;
    if (tid < 128) {
      u32x4 v = *reinterpret_cast<const u32x4*>(f2row + tid * 8);
      *reinterpret_cast<u32x4*>(&gall[tid * 8]) = v;
    } else {
      u32x4 z; z[0] = z[1] = z[2] = z[3] = 0;
      *reinterpret_cast<u32x4*>(&gall[1024 + (tid - 128) * 8]) = z;
      if (tid < 131) {
        u32x4 v = *reinterpret_cast<const u32x4*>(f2row + (tid - 128) * 8);
        *reinterpret_cast<u32x4*>(&gall[2048 + (tid - 128) * 8]) = v;
      }
    }
  }
  __syncthreads();

  // ---- step B: copies r=1..7 via aligned b128 reads + compile-time funnel shift ----
  {
    const unsigned int* g0w = reinterpret_cast<const unsigned int*>(gall);
#pragma unroll
    for (int r = 1; r < 8; ++r) {
      const int kk = (8 - r) >> 1;   // uniform: base bits[2:1]
      for (int c = tid; c < 259; c += 256) {
        int base = (c * 8 - r) & (NLAG - 1);
        int wa = (base >> 1) - kk;   // 4-aligned
        u32x4 W0 = *reinterpret_cast<const u32x4*>(&g0w[wa]);
        u32x4 W1 = *reinterpret_cast<const u32x4*>(&g0w[wa + 4]);
        unsigned int wv[8] = {W0[0], W0[1], W0[2], W0[3], W1[0], W1[1], W1[2], W1[3]};
        u32x4 ow;
        if (r & 1) {
#pragma unroll
          for (int i = 0; i < 4; ++i)
            ow[i] = (wv[kk + i] >> 16) | (wv[kk + i + 1] << 16);
        } else {
#pragma unroll
          for (int i = 0; i < 4; ++i) ow[i] = wv[kk + i];
        }
        *reinterpret_cast<u32x4*>(&gall[r * GSTRIDE + c * 8]) = ow;
      }
    }
  }
  __syncthreads();

  int rowb = iblk * 128 + wy * 64;
  // A base: element ((ks*4 + ksub*2 + l5)*256 + row)*8
  const unsigned short* abase = f1p + ((l5 * 256) + rowb + l31) * 8;
  int bb = lr * GSTRIDE;
  int ycb = 8 * l5 - 8 * lq - wx * 64;

  float pm0[16], pm1[16];
#pragma unroll
  for (int q = 0; q < 16; ++q) { pm0[q] = -3.4e38f; pm1[q] = -3.4e38f; }

  for (int tb = 0; tb < 4; ++tb) {
    int tau0 = tb * 512 + chunk * 128;  // strided for load balance
    int kA, kB;
    if (tau0 < 1024) { kA = tau0 >> 5; kB = 32; }
    else             { kA = 0;         kB = ((tau0 - 898) >> 5) + 1; }

    int yc0 = ycb - tau0;
    int yc1 = yc0 - 32;

    f32x16 acc00, acc01, acc10, acc11;
#pragma unroll
    for (int q = 0; q < 16; ++q) { acc00[q] = 0.f; acc01[q] = 0.f; acc10[q] = 0.f; acc11[q] = 0.f; }

    const unsigned short* ap0 = abase + kA * 8192;

    for (int ks = kA; ks < kB; ++ks) {
      int kbase = ks * 32;
      int y0 = (yc0 + kbase) & (NLAG - 1);
      int y1 = (yc1 + kbase) & (NLAG - 1);
      bf16x8 a00 = *reinterpret_cast<const bf16x8*>(ap0);               // rf0 ksub0
      bf16x8 a10 = *reinterpret_cast<const bf16x8*>(ap0 + 256);         // rf1 ksub0
      bf16x8 a01 = *reinterpret_cast<const bf16x8*>(ap0 + 4096);        // rf0 ksub1
      bf16x8 a11 = *reinterpret_cast<const bf16x8*>(ap0 + 4096 + 256);  // rf1 ksub1
      const unsigned short* bp0 = &gall[bb + y0];
      const unsigned short* bp1 = &gall[bb + y1];
      bf16x8 b00 = *reinterpret_cast<const bf16x8*>(bp0);       // c0 ksub0
      bf16x8 b01 = *reinterpret_cast<const bf16x8*>(bp0 + 16);  // c0 ksub1
      bf16x8 b10 = *reinterpret_cast<const bf16x8*>(bp1);       // c1 ksub0
      bf16x8 b11 = *reinterpret_cast<const bf16x8*>(bp1 + 16);  // c1 ksub1
      acc00 = __builtin_amdgcn_mfma_f32_32x32x16_bf16(a00, b00, acc00, 0, 0, 0);
      acc01 = __builtin_amdgcn_mfma_f32_32x32x16_bf16(a00, b10, acc01, 0, 0, 0);
      acc10 = __builtin_amdgcn_mfma_f32_32x32x16_bf16(a10, b00, acc10, 0, 0, 0);
      acc11 = __builtin_amdgcn_mfma_f32_32x32x16_bf16(a10, b10, acc11, 0, 0, 0);
      acc00 = __builtin_amdgcn_mfma_f32_32x32x16_bf16(a01, b01, acc00, 0, 0, 0);
      acc01 = __builtin_amdgcn_mfma_f32_32x32x16_bf16(a01, b11, acc01, 0, 0, 0);
      acc10 = __builtin_amdgcn_mfma_f32_32x32x16_bf16(a11, b01, acc10, 0, 0, 0);
      acc11 = __builtin_amdgcn_mfma_f32_32x32x16_bf16(a11, b11, acc11, 0, 0, 0);
      ap0 += 8192;
    }

    // fold this tau-block into the per-lane running max (registers only)
#pragma unroll
    for (int q = 0; q < 16; ++q) {
      pm0[q] = fmaxf(pm0[q], fmaxf(acc00[q], acc01[q]));
      pm1[q] = fmaxf(pm1[q], fmaxf(acc10[q], acc11[q]));
    }
  }

  // single cross-lane reduction per wg
#pragma unroll
  for (int rf = 0; rf < 2; ++rf) {
#pragma unroll
    for (int q = 0; q < 16; ++q) {
      float v = rf ? pm1[q] : pm0[q];
      v = fmaxf(v, __shfl_xor(v, 1, 64));
      v = fmaxf(v, __shfl_xor(v, 2, 64));
      v = fmaxf(v, __shfl_xor(v, 4, 64));
      v = fmaxf(v, __shfl_xor(v, 8, 64));
      v = fmaxf(v, __shfl_xor(v, 16, 64));
      if (l31 == 0) red[wx][wy * 64 + rf * 32 + (q & 3) + 8 * (q >> 2) + 4 * l5] = v;
    }
  }
  __syncthreads();
  if (tid < 128)
    part[(j * 4 + chunk) * 256 + iblk * 128 + tid] = fmaxf(red[0][tid], red[1][tid]);
}

// ---------------- per-row CE: dist, logsumexp, pick target ----------------
__global__ __launch_bounds__(256) void loss_kernel(
    const float* __restrict__ part, const float* __restrict__ s1,
    const float* __restrict__ s2, const int* __restrict__ speeds,
    float* __restrict__ lossrows) {
  int i = blockIdx.x;
  int jt = threadIdx.x;
  float m = part[(jt * 4 + 0) * 256 + i];
  m = fmaxf(m, part[(jt * 4 + 1) * 256 + i]);
  m = fmaxf(m, part[(jt * 4 + 2) * 256 + i]);
  m = fmaxf(m, part[(jt * 4 + 3) * 256 + i]);
  float p = s1[i] * s2[jt];
  p = (p == 0.0f) ? 1.0f : p;
  float d = m / (p * 1023.0f);

  float t = d;
  for (int mk = 1; mk <= 32; mk <<= 1) t = fmaxf(t, __shfl_xor(t, mk, 64));
  __shared__ float wmax[4], wsum[4], sel;
  if ((jt & 63) == 0) wmax[jt >> 6] = t;
  if (jt == speeds[i]) sel = d;
  __syncthreads();
  float rmax = fmaxf(fmaxf(wmax[0], wmax[1]), fmaxf(wmax[2], wmax[3]));
  float e = expf(d - rmax);
  for (int mk = 1; mk <= 32; mk <<= 1) e += __shfl_xor(e, mk, 64);
  if ((jt & 63) == 0) wsum[jt >> 6] = e;
  __syncthreads();
  if (jt == 0) {
    float sum = wsum[0] + wsum[1] + wsum[2] + wsum[3];
    lossrows[i] = rmax + logf(sum) - sel;
  }
}

__global__ __launch_bounds__(256) void sum_kernel(const float* __restrict__ lossrows,
                                                  float* __restrict__ out) {
  int t = threadIdx.x;
  float v = lossrows[t];
  for (int mk = 1; mk <= 32; mk <<= 1) v += __shfl_xor(v, mk, 64);
  __shared__ float wsh[4];
  if ((t & 63) == 0) wsh[t >> 6] = v;
  __syncthreads();
  if (t == 0) out[0] = wsh[0] + wsh[1] + wsh[2] + wsh[3];
}

extern "C" void kernel_launch(void* const* d_in, const int* in_sizes, int n_in,
                              void* d_out, int out_size, void* d_ws, size_t ws_size,
                              hipStream_t stream) {
  (void)in_sizes; (void)n_in; (void)out_size; (void)ws_size;
  const float* zis = (const float*)d_in[0];
  const float* zjs = (const float*)d_in[1];
  const int* speeds = (const int*)d_in[2];
  float* out = (float*)d_out;

  char* ws = (char*)d_ws;
  unsigned short* f1p = (unsigned short*)ws;                       // 512 KB packed A
  unsigned short* f2c = (unsigned short*)(ws + 524288);            // 512 KB
  float* s1 = (float*)(ws + 1048576);                              // 1 KB
  float* s2 = (float*)(ws + 1048576 + 1024);                       // 1 KB
  float* part = (float*)(ws + 1048576 + 2048);                     // 1 MB: [j][chunk][i]
  float* lossrows = (float*)(ws + 1048576 + 2048 + 1048576);       // 1 KB

  prep_kernel<<<512, 256, 0, stream>>>(zis, zjs, f1p, f2c, s1, s2);
  corr_kernel<<<2048, 256, 0, stream>>>(f1p, f2c, part);
  loss_kernel<<<256, 256, 0, stream>>>(part, s1, s2, speeds, lossrows);
  sum_kernel<<<1, 256, 0, stream>>>(lossrows, out);
}